// Round 1
// baseline (85.686 us; speedup 1.0000x reference)
//
#include <hip/hip_runtime.h>

// EnvironmentSpecificDecoder — MI355X bf16-MFMA implementation.
// B=32,T=64,d=128,L=64,H=256,H2=128,N_ENVS=8. out = [mu(262144) | sigma(262144)] fp32.
//
// Folding: h1 = relu( (A^T Z) @ (W_sig@W1e[e]) + (b_sig@W1e[e] + b1e[e]) )
// Per (b,t): m1: M1^T = Z^T @ A          (64x128x128)
//            m2: P    = M1 @ Wsw1[e]     (128x64x256, h in 2 chunks of 128)
//            m3: OUT  = relu(P+bias1) @ W2[e]   (vector + shfl reduce, N=2)
//            mc: Hc^T = Wc^T @ Zc^T      (128x64x128), contrib = relu(Hc+bc)@Wo (shfl)

typedef __attribute__((ext_vector_type(8))) short short8;   // 8 x bf16 (4 VGPR)
typedef __attribute__((ext_vector_type(4))) float f32x4;

#define MFMA16(a, b, c) __builtin_amdgcn_mfma_f32_16x16x32_bf16((a), (b), (c), 0, 0, 0)

__device__ __forceinline__ unsigned short f2bf(float f) {
  union { float f; unsigned u; } v; v.f = f;
  unsigned r = v.u + 0x7fffu + ((v.u >> 16) & 1u);  // RNE
  return (unsigned short)(r >> 16);
}

// ---------------- setup: fold weights, transpose, cast to bf16 (runs every launch) ----
__global__ void setup_k(const float* __restrict__ A, const float* __restrict__ W_sig,
                        const float* __restrict__ b_sig, const float* __restrict__ W1e,
                        const float* __restrict__ b1e, const float* __restrict__ Wc,
                        unsigned short* __restrict__ wsw1t, unsigned short* __restrict__ at,
                        unsigned short* __restrict__ wct, float* __restrict__ bias1) {
  int blk = blockIdx.x, tid = threadIdx.x;
  if (blk < 512) {                       // Wsw1t[e][h][l] = bf16(sum_h1 W_sig[l,h1]*W1e[e,h1,h])
    int e = blk >> 6, l = blk & 63, h = tid;
    const float* w1 = W1e + e * 65536 + h;
    const float* ws = W_sig + l * 256;
    float acc = 0.f;
    #pragma unroll 8
    for (int h1 = 0; h1 < 256; ++h1) acc = fmaf(ws[h1], w1[h1 * 256], acc);
    wsw1t[(e * 256 + h) * 64 + l] = f2bf(acc);
  } else if (blk < 576) {                // At[i][j] = bf16(A[j][i])
    int idx = (blk - 512) * 256 + tid, i = idx >> 7, j = idx & 127;
    at[idx] = f2bf(A[j * 128 + i]);
  } else if (blk < 608) {                // Wct[h'][l] = bf16(Wc[l][h'])
    int idx = (blk - 576) * 256 + tid, h = idx >> 6, l = idx & 63;
    wct[idx] = f2bf(Wc[l * 128 + h]);
  } else {                               // bias1[e][h] = b_sig@W1e[e] + b1e[e]
    int e = blk - 608, h = tid;
    const float* w1 = W1e + e * 65536 + h;
    float acc = b1e[e * 256 + h];
    for (int h1 = 0; h1 < 256; ++h1) acc = fmaf(b_sig[h1], w1[h1 * 256], acc);
    bias1[e * 256 + h] = acc;
  }
}

// ---------------- main kernel: one 512-thread (8-wave) block per (b,t) ----------------
// LDS map (69.5 KB -> 2 wg/CU):
//  R1      0: Zt  [64 l][128 j] bf16  (swizzle swzT(l))
//  R2  16384: Zcb [128 d][64 l]  ->  M1buf [128 i][64 l]   (swz8(row))
//  R3  32768: At half [128 i][64 jj]                        (swz8(i))
//  R4  49152: Wct [128 h'][64 l] -> Wsw1t chunk [128 h][64 l] (swz8(row))
//  65536+: misc (bias1, W2, bc|Wo, contrib, out staging, scalars)
__global__ __launch_bounds__(512, 4) void dec_k(
    const float* __restrict__ zs, const float* __restrict__ zcr,
    const int* __restrict__ regime, const float* __restrict__ W2e,
    const float* __restrict__ b2e, const float* __restrict__ bc,
    const float* __restrict__ Wo, const float* __restrict__ bo,
    const unsigned short* __restrict__ wsw1t, const unsigned short* __restrict__ at,
    const unsigned short* __restrict__ wct, const float* __restrict__ bias1,
    float* __restrict__ out) {
  __shared__ __align__(16) char sm[71200];
  const int bt = ((blockIdx.x & 7) << 8) | (blockIdx.x >> 3);  // XCD swizzle (2048%8==0)
  const int tid = threadIdx.x;
  const int lane = tid & 63, wave = tid >> 6, lg = lane >> 4, l15 = lane & 15;
  int e = regime[bt >> 6]; if (e >= 8) e = 0;

  const float* Z  = zs  + (size_t)bt * 8192;
  const float* Zc = zcr + (size_t)bt * 8192;
  const uint4* at4  = (const uint4*)at;
  const uint4* wct4 = (const uint4*)wct;
  const uint4* w14  = (const uint4*)wsw1t;

  float* s_bias1   = (float*)(sm + 65536);  // 256 f32
  float* s_W2      = (float*)(sm + 66560);  // 512 f32 [h][k]
  float* s_bcWo    = (float*)(sm + 68608);  // 128x2 f32 interleaved
  float* s_contrib = (float*)(sm + 69632);  // 128 f32
  float* s_out     = (float*)(sm + 70144);  // 256 f32
  float* s_scal    = (float*)(sm + 71168);  // b2[0], b2[1], bo

  // ---- stage-1 global loads ----
  float4 zcv[4];
  #pragma unroll
  for (int k = 0; k < 4; ++k) {
    int g = k * 512 + tid, d = g >> 4, l0 = (g & 15) * 4;
    zcv[k] = *(const float4*)(Zc + d * 64 + l0);
  }
  uint4 wctv[2];
  #pragma unroll
  for (int k = 0; k < 2; ++k) wctv[k] = wct4[k * 512 + tid];
  float4 z0v[2], z1v[2];
  #pragma unroll
  for (int k = 0; k < 2; ++k) {
    int g = k * 512 + tid, j = (g >> 4) * 2, l0 = (g & 15) * 4;
    const float* p = Z + j * 64 + l0;
    z0v[k] = *(const float4*)p;
    z1v[k] = *(const float4*)(p + 64);
  }
  uint4 atv[2];
  #pragma unroll
  for (int k = 0; k < 2; ++k) {
    int it = k * 512 + tid;
    atv[k] = at4[(it >> 3) * 16 + (it & 7)];   // At rows are 16 uint4; half0 = first 8
  }
  float bias1v = 0.f; if (tid < 256) bias1v = bias1[e * 256 + tid];
  float w2v = W2e[e * 512 + tid];
  float bcv = 0.f, wov = 0.f;
  if (tid < 128) { bcv = bc[tid]; wov = Wo[tid]; }

  // ---- stage-1 LDS writes ----
  if (tid < 256) s_bias1[tid] = bias1v;
  s_W2[tid] = w2v;
  if (tid < 128) { s_bcWo[2 * tid] = bcv; s_bcWo[2 * tid + 1] = wov; }
  if (tid == 0) { s_scal[0] = b2e[2 * e]; s_scal[1] = b2e[2 * e + 1]; s_scal[2] = bo[0]; }

  #pragma unroll
  for (int k = 0; k < 4; ++k) {           // Zcb[d][l] bf16, swz8(d)
    int g = k * 512 + tid, d = g >> 4, l0 = (g & 15) * 4;
    unsigned lo = (unsigned)f2bf(zcv[k].x) | ((unsigned)f2bf(zcv[k].y) << 16);
    unsigned hi = (unsigned)f2bf(zcv[k].z) | ((unsigned)f2bf(zcv[k].w) << 16);
    int a = (d * 128 + l0 * 2) ^ ((d & 7) << 4);
    *(unsigned long long*)(sm + 16384 + a) = ((unsigned long long)hi << 32) | lo;
  }
  #pragma unroll
  for (int k = 0; k < 2; ++k) {           // Wct copy, swz8(h')
    int it = k * 512 + tid, h = it >> 3;
    *(uint4*)(sm + 49152 + ((it * 16) ^ ((h & 7) << 4))) = wctv[k];
  }
  #pragma unroll
  for (int k = 0; k < 2; ++k) {           // Zt[l][j] = Z[j][l] transpose, swzT(l)
    int g = k * 512 + tid, j = (g >> 4) * 2, l0 = (g & 15) * 4;
    float a0[4] = {z0v[k].x, z0v[k].y, z0v[k].z, z0v[k].w};
    float a1[4] = {z1v[k].x, z1v[k].y, z1v[k].z, z1v[k].w};
    #pragma unroll
    for (int i2 = 0; i2 < 4; ++i2) {
      int l = l0 + i2;
      unsigned v = (unsigned)f2bf(a0[i2]) | ((unsigned)f2bf(a1[i2]) << 16);
      int a = (l * 256 + j * 2) ^ ((((l >> 2) ^ l) & 7) << 4);
      *(unsigned*)(sm + a) = v;
    }
  }
  #pragma unroll
  for (int k = 0; k < 2; ++k) {           // At half0, swz8(i)
    int it = k * 512 + tid, i = it >> 3;
    *(uint4*)(sm + 32768 + ((it * 16) ^ ((i & 7) << 4))) = atv[k];
  }
  __syncthreads();

  // ---- issue stage-2 loads (consumed later; overlap with mc compute) ----
  uint4 at2v[2];
  #pragma unroll
  for (int k = 0; k < 2; ++k) {
    int it = k * 512 + tid;
    at2v[k] = at4[(it >> 3) * 16 + 8 + (it & 7)];          // At half1 (j 64..127)
  }
  uint4 ws1v[2];
  #pragma unroll
  for (int k = 0; k < 2; ++k) {
    int it = k * 512 + tid;
    ws1v[k] = w14[e * 2048 + (it >> 3) * 8 + (it & 7)];    // Wsw1t chunk0 (h 0..127)
  }

  // ---- mc: Hc^T = Wc^T @ Zc^T. wave owns d-tile = wave, all 8 h'-tiles ----
  f32x4 accc[8];
  #pragma unroll
  for (int ht = 0; ht < 8; ++ht) accc[ht] = (f32x4){0.f, 0.f, 0.f, 0.f};
  #pragma unroll
  for (int ks = 0; ks < 2; ++ks) {
    int kb = (lg * 8 + ks * 32) * 2;
    int dcol = wave * 16 + l15;
    short8 bfr = *(const short8*)(sm + 16384 + ((dcol * 128 + kb) ^ ((dcol & 7) << 4)));
    #pragma unroll
    for (int ht = 0; ht < 8; ++ht) {
      int hr = ht * 16 + l15;
      short8 afr = *(const short8*)(sm + 49152 + ((hr * 128 + kb) ^ ((hr & 7) << 4)));
      accc[ht] = MFMA16(afr, bfr, accc[ht]);
    }
  }
  {  // contrib[d] = sum_h' relu(Hc+bc)*Wo ; reduce rows over lg groups
    float s = 0.f;
    #pragma unroll
    for (int ht = 0; ht < 8; ++ht) {
      #pragma unroll
      for (int r = 0; r < 4; ++r) {
        int hp = ht * 16 + lg * 4 + r;
        float2 bw = *(const float2*)(s_bcWo + 2 * hp);
        float v = fmaxf(accc[ht][r] + bw.x, 0.f);
        s = fmaf(v, bw.y, s);
      }
    }
    s += __shfl_xor(s, 16);
    s += __shfl_xor(s, 32);
    if (lane < 16) s_contrib[wave * 16 + lane] = s;
  }
  __syncthreads();

  // ---- write Wsw1t chunk0 into R4 (Wct dead) ; m1 phase A (j 0..63) ----
  #pragma unroll
  for (int k = 0; k < 2; ++k) {
    int it = k * 512 + tid, h = it >> 3;
    *(uint4*)(sm + 49152 + ((it * 16) ^ ((h & 7) << 4))) = ws1v[k];
  }
  const int ltile = wave >> 1, ibase = (wave & 1) * 4;
  const int lrow = ltile * 16 + l15;
  const int zsw = ((((lrow >> 2) ^ lrow) & 7) << 4);
  f32x4 acc1[4];
  #pragma unroll
  for (int it = 0; it < 4; ++it) acc1[it] = (f32x4){0.f, 0.f, 0.f, 0.f};
  #pragma unroll
  for (int ks = 0; ks < 2; ++ks) {
    int zk = (lg * 8 + ks * 32) * 2;
    short8 afr = *(const short8*)(sm + ((lrow * 256 + zk) ^ zsw));
    #pragma unroll
    for (int it = 0; it < 4; ++it) {
      int icol = (ibase + it) * 16 + l15;
      short8 bfr = *(const short8*)(sm + 32768 + ((icol * 128 + zk) ^ ((icol & 7) << 4)));
      acc1[it] = MFMA16(afr, bfr, acc1[it]);
    }
  }
  __syncthreads();

  // ---- swap in At half1; issue Wsw1t chunk1 loads ----
  #pragma unroll
  for (int k = 0; k < 2; ++k) {
    int it = k * 512 + tid, i = it >> 3;
    *(uint4*)(sm + 32768 + ((it * 16) ^ ((i & 7) << 4))) = at2v[k];
  }
  uint4 ws1bv[2];
  #pragma unroll
  for (int k = 0; k < 2; ++k) {
    int it = k * 512 + tid;
    ws1bv[k] = w14[e * 2048 + (128 + (it >> 3)) * 8 + (it & 7)];  // h 128..255
  }
  __syncthreads();

  // ---- m1 phase B (j 64..127) + store M1buf[i][l] into R2 (Zcb dead) ----
  #pragma unroll
  for (int ks = 2; ks < 4; ++ks) {
    int zk = (lg * 8 + ks * 32) * 2;
    int ak = (lg * 8 + (ks - 2) * 32) * 2;
    short8 afr = *(const short8*)(sm + ((lrow * 256 + zk) ^ zsw));
    #pragma unroll
    for (int it = 0; it < 4; ++it) {
      int icol = (ibase + it) * 16 + l15;
      short8 bfr = *(const short8*)(sm + 32768 + ((icol * 128 + ak) ^ ((icol & 7) << 4)));
      acc1[it] = MFMA16(afr, bfr, acc1[it]);
    }
  }
  {
    int l0 = ltile * 16 + lg * 4;
    #pragma unroll
    for (int it = 0; it < 4; ++it) {
      int icol = (ibase + it) * 16 + l15;
      unsigned lo = (unsigned)f2bf(acc1[it][0]) | ((unsigned)f2bf(acc1[it][1]) << 16);
      unsigned hi = (unsigned)f2bf(acc1[it][2]) | ((unsigned)f2bf(acc1[it][3]) << 16);
      int a = (icol * 128 + l0 * 2) ^ ((icol & 7) << 4);
      *(unsigned long long*)(sm + 16384 + a) = ((unsigned long long)hi << 32) | lo;
    }
  }
  __syncthreads();

  // ---- m2 (2 h-chunks) + m3 epilogue partials. wave owns i-tile = wave ----
  float v0[4] = {0.f, 0.f, 0.f, 0.f}, v1[4] = {0.f, 0.f, 0.f, 0.f};
  #pragma unroll
  for (int c = 0; c < 2; ++c) {
    if (c == 1) {
      __syncthreads();
      #pragma unroll
      for (int k = 0; k < 2; ++k) {
        int it = k * 512 + tid, h = it >> 3;
        *(uint4*)(sm + 49152 + ((it * 16) ^ ((h & 7) << 4))) = ws1bv[k];
      }
      __syncthreads();
    }
    f32x4 acc2[8];
    #pragma unroll
    for (int ht = 0; ht < 8; ++ht) acc2[ht] = (f32x4){0.f, 0.f, 0.f, 0.f};
    #pragma unroll
    for (int ks = 0; ks < 2; ++ks) {
      int kk = (lg * 8 + ks * 32) * 2;
      int irow = wave * 16 + l15;
      short8 afr = *(const short8*)(sm + 16384 + ((irow * 128 + kk) ^ ((irow & 7) << 4)));
      #pragma unroll
      for (int ht = 0; ht < 8; ++ht) {
        int hl = ht * 16 + l15;
        short8 bfr = *(const short8*)(sm + 49152 + ((hl * 128 + kk) ^ ((hl & 7) << 4)));
        acc2[ht] = MFMA16(afr, bfr, acc2[ht]);
      }
    }
    #pragma unroll
    for (int ht = 0; ht < 8; ++ht) {
      int h = c * 128 + ht * 16 + l15;
      float b1v = s_bias1[h];
      float2 w2 = *(const float2*)(s_W2 + 2 * h);
      #pragma unroll
      for (int r = 0; r < 4; ++r) {
        float p = fmaxf(acc2[ht][r] + b1v, 0.f);
        v0[r] = fmaf(p, w2.x, v0[r]);
        v1[r] = fmaf(p, w2.y, v1[r]);
      }
    }
  }

  // ---- reduce over 16-lane column groups; finalize mu/sigma ----
  #pragma unroll
  for (int m = 1; m < 16; m <<= 1) {
    #pragma unroll
    for (int r = 0; r < 4; ++r) {
      v0[r] += __shfl_xor(v0[r], m);
      v1[r] += __shfl_xor(v1[r], m);
    }
  }
  float b2_0 = s_scal[0], b2_1 = s_scal[1], bo0 = s_scal[2];
  if (l15 == 0) {
    #pragma unroll
    for (int r = 0; r < 4; ++r) {
      int row = wave * 16 + lg * 4 + r;
      float mu = v0[r] + b2_0 + bo0 + s_contrib[row];
      float x = v1[r] + b2_1;
      float sg = fmaxf(x, 0.f) + log1pf(expf(-fabsf(x))) + 0.01f;  // softplus + MIN_SIGMA
      s_out[row] = mu;
      s_out[128 + row] = sg;
    }
  }
  __syncthreads();
  if (tid < 256) {
    float v = s_out[tid];
    size_t o = (tid < 128) ? ((size_t)bt * 128 + tid)
                           : ((size_t)262144 + (size_t)bt * 128 + (tid - 128));
    out[o] = v;
  }
}

extern "C" void kernel_launch(void* const* d_in, const int* in_sizes, int n_in,
                              void* d_out, int out_size, void* d_ws, size_t ws_size,
                              hipStream_t stream) {
  const float* zs    = (const float*)d_in[0];
  const float* zcr   = (const float*)d_in[1];
  const float* A     = (const float*)d_in[2];
  const int*   reg   = (const int*)d_in[3];
  const float* W_sig = (const float*)d_in[4];
  const float* b_sig = (const float*)d_in[5];
  const float* W1e   = (const float*)d_in[6];
  const float* b1e   = (const float*)d_in[7];
  const float* W2e   = (const float*)d_in[8];
  const float* b2e   = (const float*)d_in[9];
  const float* Wc    = (const float*)d_in[10];
  const float* bcp   = (const float*)d_in[11];
  const float* Wo    = (const float*)d_in[12];
  const float* bo    = (const float*)d_in[13];

  unsigned short* wsw1t = (unsigned short*)d_ws;            // 8*256*64 bf16 = 256 KB
  unsigned short* at    = wsw1t + 131072;                   // 128*128 bf16  = 32 KB
  unsigned short* wct   = at + 16384;                       // 128*64 bf16   = 16 KB
  float* bias1          = (float*)(wct + 8192);             // 8*256 f32     = 8 KB

  setup_k<<<616, 256, 0, stream>>>(A, W_sig, b_sig, W1e, b1e, Wc, wsw1t, at, wct, bias1);
  dec_k<<<2048, 512, 0, stream>>>(zs, zcr, reg, W2e, b2e, bcp, Wo, bo,
                                  wsw1t, at, wct, bias1, (float*)d_out);
}

// Round 2
// 66.991 us; speedup vs baseline: 1.2791x; 1.2791x over previous
//
#include <hip/hip_runtime.h>

// EnvironmentSpecificDecoder — MI355X bf16-MFMA implementation, round 2.
// B=32,T=64,d=128,L=64,H=256,H2=128,N_ENVS=8. out = [mu(262144) | sigma(262144)] fp32.
//
// Folding: h1 = relu( (A^T Z) @ (W_sig@W1e[e]) + (b_sig@W1e[e] + b1e[e]) )
// Per (b,t): m1: M1^T = Z^T @ A          (64x128x128)
//            m2: P    = M1 @ Wsw1[e]     (128x64x256, h in 2 chunks of 128)
//            m3: OUT  = relu(P+bias1) @ W2[e]   (vector + shfl reduce, N=2)
//            mc: Hc^T = Wc^T @ Zc^T      (128x64x128), contrib = relu(Hc+bc)@Wo (shfl)
//
// Round-2 change: all weight tiles staged via global_load_lds (width 16) from
// PRE-SWIZZLED sources in d_ws (granule g -> g^(row&7), involution), killing
// the register-staged arrays that spilled (~100 MB/dispatch scratch writes).

typedef __attribute__((ext_vector_type(8))) short short8;   // 8 x bf16 (4 VGPR)
typedef __attribute__((ext_vector_type(4))) float f32x4;

#define MFMA16(a, b, c) __builtin_amdgcn_mfma_f32_16x16x32_bf16((a), (b), (c), 0, 0, 0)

__device__ __forceinline__ unsigned short f2bf(float f) {
  union { float f; unsigned u; } v; v.f = f;
  unsigned r = v.u + 0x7fffu + ((v.u >> 16) & 1u);  // RNE
  return (unsigned short)(r >> 16);
}

__device__ __forceinline__ void gload16(const void* gsrc, void* ldsdst) {
  __builtin_amdgcn_global_load_lds(
      (const __attribute__((address_space(1))) unsigned int*)gsrc,
      (__attribute__((address_space(3))) unsigned int*)ldsdst, 16, 0, 0);
}

// ---------------- setup: fold weights, transpose, cast bf16, PRE-SWIZZLE ----------------
// Pre-swizzle: within each 128B row (8 x 16B granules), granule g holds data of
// granule (g ^ (row&7)), so that linear global_load_lds + XOR-swizzled ds_read works.
__global__ void setup_k(const float* __restrict__ A, const float* __restrict__ W_sig,
                        const float* __restrict__ b_sig, const float* __restrict__ W1e,
                        const float* __restrict__ b1e, const float* __restrict__ Wc,
                        unsigned short* __restrict__ wsw1s, unsigned short* __restrict__ ats,
                        unsigned short* __restrict__ wcts, float* __restrict__ bias1) {
  int blk = blockIdx.x, tid = threadIdx.x;
  if (blk < 512) {                       // Wsw1[l][h] = sum_h1 W_sig[l,h1]*W1e[e,h1,h]
    int e = blk >> 6, l = blk & 63, h = tid;
    const float* w1 = W1e + e * 65536 + h;
    const float* ws = W_sig + l * 256;
    float acc = 0.f;
    #pragma unroll 8
    for (int h1 = 0; h1 < 256; ++h1) acc = fmaf(ws[h1], w1[h1 * 256], acc);
    // store into chunk c = h>>7 as [hh][l] rows, swizzled
    int c = h >> 7, hh = h & 127, gl = l >> 3, e8 = l & 7;
    wsw1s[((e * 2 + c) * 128 + hh) * 64 + ((gl ^ (hh & 7)) << 3) + e8] = f2bf(acc);
  } else if (blk < 576) {                // At[i][j] = A[j][i], halves of j, swizzled
    int idx = (blk - 512) * 256 + tid, i = idx >> 7, j = idx & 127;
    int half = j >> 6, jj = j & 63, gj = jj >> 3, e8 = jj & 7;
    ats[half * 8192 + i * 64 + ((gj ^ (i & 7)) << 3) + e8] = f2bf(A[j * 128 + i]);
  } else if (blk < 608) {                // Wct[h'][l] = Wc[l][h'], swizzled
    int idx = (blk - 576) * 256 + tid, h = idx >> 6, l = idx & 63;
    wcts[h * 64 + (((l >> 3) ^ (h & 7)) << 3) + (l & 7)] = f2bf(Wc[l * 128 + h]);
  } else {                               // bias1[e][h] = b_sig@W1e[e] + b1e[e]
    int e = blk - 608, h = tid;
    const float* w1 = W1e + e * 65536 + h;
    float acc = b1e[e * 256 + h];
    for (int h1 = 0; h1 < 256; ++h1) acc = fmaf(b_sig[h1], w1[h1 * 256], acc);
    bias1[e * 256 + h] = acc;
  }
}

// ---------------- main kernel: one 512-thread (8-wave) block per (b,t) ----------------
// LDS map (69.5 KB -> 2 wg/CU):
//  R1      0: Zt  [64 l][128 j] bf16  (swizzle swzT(l))
//  R2  16384: Zcb [128 d][64 l]  ->  M1buf [128 i][64 l]   (swz8(row))
//  R3  32768: At half [128 i][64 jj]                        (swz8(i))
//  R4  49152: Wct [128 h'][64 l] -> Wsw1t chunk [128 h][64 l] (swz8(row))
//  65536+: misc (bias1, W2, bc|Wo, contrib, out staging, scalars)
__global__ __launch_bounds__(512, 4) void dec_k(
    const float* __restrict__ zs, const float* __restrict__ zcr,
    const int* __restrict__ regime, const float* __restrict__ W2e,
    const float* __restrict__ b2e, const float* __restrict__ bc,
    const float* __restrict__ Wo, const float* __restrict__ bo,
    const unsigned short* __restrict__ wsw1s, const unsigned short* __restrict__ ats,
    const unsigned short* __restrict__ wcts, const float* __restrict__ bias1,
    float* __restrict__ out) {
  __shared__ __align__(16) char sm[71200];
  const int bt = ((blockIdx.x & 7) << 8) | (blockIdx.x >> 3);  // XCD swizzle (2048%8==0)
  const int tid = threadIdx.x;
  const int lane = tid & 63, wave = tid >> 6, lg = lane >> 4, l15 = lane & 15;
  int e = regime[bt >> 6]; if (e >= 8) e = 0;

  const float* Z  = zs  + (size_t)bt * 8192;
  const float* Zc = zcr + (size_t)bt * 8192;

  float* s_bias1   = (float*)(sm + 65536);  // 256 f32
  float* s_W2      = (float*)(sm + 66560);  // 512 f32 [h][k]
  float* s_bcWo    = (float*)(sm + 68608);  // 128x2 f32 interleaved
  float* s_contrib = (float*)(sm + 69632);  // 128 f32
  float* s_out     = (float*)(sm + 70144);  // 256 f32
  float* s_scal    = (float*)(sm + 71168);  // b2[0], b2[1], bo

  // stage a pre-swizzled 16KB tile (1024 granules) into LDS region, 2 calls/thread
  auto stage_region = [&](const unsigned short* src, int lds_off) {
    #pragma unroll
    for (int k = 0; k < 2; ++k)
      gload16((const char*)src + (k * 512 + tid) * 16,
              sm + lds_off + (k * 512 + wave * 64) * 16);
  };

  // ---- issue async weight staging first (in flight during Z conversion) ----
  stage_region(wcts, 49152);          // Wct -> R4
  stage_region(ats, 32768);           // At half0 -> R3

  // ---- Zc: fp32 -> bf16 into R2 as [d][l], swz8(d) ----
  float4 zcv[4];
  #pragma unroll
  for (int k = 0; k < 4; ++k) {
    int g = k * 512 + tid, d = g >> 4, l0 = (g & 15) * 4;
    zcv[k] = *(const float4*)(Zc + d * 64 + l0);
  }
  #pragma unroll
  for (int k = 0; k < 4; ++k) {
    int g = k * 512 + tid, d = g >> 4, l0 = (g & 15) * 4;
    unsigned lo = (unsigned)f2bf(zcv[k].x) | ((unsigned)f2bf(zcv[k].y) << 16);
    unsigned hi = (unsigned)f2bf(zcv[k].z) | ((unsigned)f2bf(zcv[k].w) << 16);
    int a = (d * 128 + l0 * 2) ^ ((d & 7) << 4);
    *(unsigned long long*)(sm + 16384 + a) = ((unsigned long long)hi << 32) | lo;
  }

  // ---- Z: fp32 -> bf16 TRANSPOSED into R1 as [l][j], swzT(l) ----
  float4 z0v[2], z1v[2];
  #pragma unroll
  for (int k = 0; k < 2; ++k) {
    int g = k * 512 + tid, j = (g >> 4) * 2, l0 = (g & 15) * 4;
    const float* p = Z + j * 64 + l0;
    z0v[k] = *(const float4*)p;
    z1v[k] = *(const float4*)(p + 64);
  }
  #pragma unroll
  for (int k = 0; k < 2; ++k) {
    int g = k * 512 + tid, j = (g >> 4) * 2, l0 = (g & 15) * 4;
    float a0[4] = {z0v[k].x, z0v[k].y, z0v[k].z, z0v[k].w};
    float a1[4] = {z1v[k].x, z1v[k].y, z1v[k].z, z1v[k].w};
    #pragma unroll
    for (int i2 = 0; i2 < 4; ++i2) {
      int l = l0 + i2;
      unsigned v = (unsigned)f2bf(a0[i2]) | ((unsigned)f2bf(a1[i2]) << 16);
      int a = (l * 256 + j * 2) ^ ((((l >> 2) ^ l) & 7) << 4);
      *(unsigned*)(sm + a) = v;
    }
  }

  // ---- misc small loads -> LDS ----
  if (tid < 256) s_bias1[tid] = bias1[e * 256 + tid];
  s_W2[tid] = W2e[e * 512 + tid];
  if (tid < 128) { s_bcWo[2 * tid] = bc[tid]; s_bcWo[2 * tid + 1] = Wo[tid]; }
  if (tid == 0) { s_scal[0] = b2e[2 * e]; s_scal[1] = b2e[2 * e + 1]; s_scal[2] = bo[0]; }

  __syncthreads();   // sync1: drains gload_lds (vmcnt 0) + LDS writes

  // ---- mc: Hc^T = Wc^T @ Zc^T. wave owns d-tile = wave, all 8 h'-tiles ----
  f32x4 accc[8];
  #pragma unroll
  for (int ht = 0; ht < 8; ++ht) accc[ht] = (f32x4){0.f, 0.f, 0.f, 0.f};
  #pragma unroll
  for (int ks = 0; ks < 2; ++ks) {
    int kb = (lg * 8 + ks * 32) * 2;
    int dcol = wave * 16 + l15;
    short8 bfr = *(const short8*)(sm + 16384 + ((dcol * 128 + kb) ^ ((dcol & 7) << 4)));
    #pragma unroll
    for (int ht = 0; ht < 8; ++ht) {
      int hr = ht * 16 + l15;
      short8 afr = *(const short8*)(sm + 49152 + ((hr * 128 + kb) ^ ((hr & 7) << 4)));
      accc[ht] = MFMA16(afr, bfr, accc[ht]);
    }
  }
  {  // contrib[d] = sum_h' relu(Hc+bc)*Wo ; reduce rows over lg groups
    float s = 0.f;
    #pragma unroll
    for (int ht = 0; ht < 8; ++ht) {
      #pragma unroll
      for (int r = 0; r < 4; ++r) {
        int hp = ht * 16 + lg * 4 + r;
        float2 bw = *(const float2*)(s_bcWo + 2 * hp);
        float v = fmaxf(accc[ht][r] + bw.x, 0.f);
        s = fmaf(v, bw.y, s);
      }
    }
    s += __shfl_xor(s, 16);
    s += __shfl_xor(s, 32);
    if (lane < 16) s_contrib[wave * 16 + lane] = s;
  }
  __syncthreads();   // sync2: Wct reads retired

  // ---- issue Wsw1 chunk0 -> R4 (flies during m1A) ; m1 phase A (j 0..63) ----
  stage_region(wsw1s + (size_t)e * 16384, 49152);

  const int ltile = wave >> 1, ibase = (wave & 1) * 4;
  const int lrow = ltile * 16 + l15;
  const int zsw = ((((lrow >> 2) ^ lrow) & 7) << 4);
  f32x4 acc1[4];
  #pragma unroll
  for (int it = 0; it < 4; ++it) acc1[it] = (f32x4){0.f, 0.f, 0.f, 0.f};
  #pragma unroll
  for (int ks = 0; ks < 2; ++ks) {
    int zk = (lg * 8 + ks * 32) * 2;
    short8 afr = *(const short8*)(sm + ((lrow * 256 + zk) ^ zsw));
    #pragma unroll
    for (int it = 0; it < 4; ++it) {
      int icol = (ibase + it) * 16 + l15;
      short8 bfr = *(const short8*)(sm + 32768 + ((icol * 128 + zk) ^ ((icol & 7) << 4)));
      acc1[it] = MFMA16(afr, bfr, acc1[it]);
    }
  }
  __syncthreads();   // sync3: At-h0 reads retired, chunk0 drained

  // ---- issue At half1 -> R3 ----
  stage_region(ats + 8192, 32768);
  __syncthreads();   // sync4: At-h1 ready

  // ---- m1 phase B (j 64..127) + store M1buf[i][l] into R2 (Zcb dead) ----
  #pragma unroll
  for (int ks = 2; ks < 4; ++ks) {
    int zk = (lg * 8 + ks * 32) * 2;
    int ak = (lg * 8 + (ks - 2) * 32) * 2;
    short8 afr = *(const short8*)(sm + ((lrow * 256 + zk) ^ zsw));
    #pragma unroll
    for (int it = 0; it < 4; ++it) {
      int icol = (ibase + it) * 16 + l15;
      short8 bfr = *(const short8*)(sm + 32768 + ((icol * 128 + ak) ^ ((icol & 7) << 4)));
      acc1[it] = MFMA16(afr, bfr, acc1[it]);
    }
  }
  {
    int l0 = ltile * 16 + lg * 4;
    #pragma unroll
    for (int it = 0; it < 4; ++it) {
      int icol = (ibase + it) * 16 + l15;
      unsigned lo = (unsigned)f2bf(acc1[it][0]) | ((unsigned)f2bf(acc1[it][1]) << 16);
      unsigned hi = (unsigned)f2bf(acc1[it][2]) | ((unsigned)f2bf(acc1[it][3]) << 16);
      int a = (icol * 128 + l0 * 2) ^ ((icol & 7) << 4);
      *(unsigned long long*)(sm + 16384 + a) = ((unsigned long long)hi << 32) | lo;
    }
  }
  __syncthreads();   // sync5: M1 ready, Wsw1 chunk0 ready (drained at sync3/4)

  // ---- m2 (2 h-chunks) + m3 epilogue partials. wave owns i-tile = wave ----
  float v0[4] = {0.f, 0.f, 0.f, 0.f}, v1[4] = {0.f, 0.f, 0.f, 0.f};
  #pragma unroll
  for (int c = 0; c < 2; ++c) {
    if (c == 1) {
      __syncthreads();   // sync6: chunk0 reads retired
      stage_region(wsw1s + (size_t)e * 16384 + 8192, 49152);
      __syncthreads();   // sync7: chunk1 ready
    }
    f32x4 acc2[8];
    #pragma unroll
    for (int ht = 0; ht < 8; ++ht) acc2[ht] = (f32x4){0.f, 0.f, 0.f, 0.f};
    #pragma unroll
    for (int ks = 0; ks < 2; ++ks) {
      int kk = (lg * 8 + ks * 32) * 2;
      int irow = wave * 16 + l15;
      short8 afr = *(const short8*)(sm + 16384 + ((irow * 128 + kk) ^ ((irow & 7) << 4)));
      #pragma unroll
      for (int ht = 0; ht < 8; ++ht) {
        int hl = ht * 16 + l15;
        short8 bfr = *(const short8*)(sm + 49152 + ((hl * 128 + kk) ^ ((hl & 7) << 4)));
        acc2[ht] = MFMA16(afr, bfr, acc2[ht]);
      }
    }
    #pragma unroll
    for (int ht = 0; ht < 8; ++ht) {
      int h = c * 128 + ht * 16 + l15;
      float b1v = s_bias1[h];
      float2 w2 = *(const float2*)(s_W2 + 2 * h);
      #pragma unroll
      for (int r = 0; r < 4; ++r) {
        float p = fmaxf(acc2[ht][r] + b1v, 0.f);
        v0[r] = fmaf(p, w2.x, v0[r]);
        v1[r] = fmaf(p, w2.y, v1[r]);
      }
    }
  }

  // ---- reduce over 16-lane column groups; finalize mu/sigma ----
  #pragma unroll
  for (int m = 1; m < 16; m <<= 1) {
    #pragma unroll
    for (int r = 0; r < 4; ++r) {
      v0[r] += __shfl_xor(v0[r], m);
      v1[r] += __shfl_xor(v1[r], m);
    }
  }
  float b2_0 = s_scal[0], b2_1 = s_scal[1], bo0 = s_scal[2];
  if (l15 == 0) {
    #pragma unroll
    for (int r = 0; r < 4; ++r) {
      int row = wave * 16 + lg * 4 + r;
      float mu = v0[r] + b2_0 + bo0 + s_contrib[row];
      float x = v1[r] + b2_1;
      float sg = fmaxf(x, 0.f) + log1pf(expf(-fabsf(x))) + 0.01f;  // softplus + MIN_SIGMA
      s_out[row] = mu;
      s_out[128 + row] = sg;
    }
  }
  __syncthreads();
  if (tid < 256) {
    float v = s_out[tid];
    size_t o = (tid < 128) ? ((size_t)bt * 128 + tid)
                           : ((size_t)262144 + (size_t)bt * 128 + (tid - 128));
    out[o] = v;
  }
}

extern "C" void kernel_launch(void* const* d_in, const int* in_sizes, int n_in,
                              void* d_out, int out_size, void* d_ws, size_t ws_size,
                              hipStream_t stream) {
  const float* zs    = (const float*)d_in[0];
  const float* zcr   = (const float*)d_in[1];
  const float* A     = (const float*)d_in[2];
  const int*   reg   = (const int*)d_in[3];
  const float* W_sig = (const float*)d_in[4];
  const float* b_sig = (const float*)d_in[5];
  const float* W1e   = (const float*)d_in[6];
  const float* b1e   = (const float*)d_in[7];
  const float* W2e   = (const float*)d_in[8];
  const float* b2e   = (const float*)d_in[9];
  const float* Wc    = (const float*)d_in[10];
  const float* bcp   = (const float*)d_in[11];
  const float* Wo    = (const float*)d_in[12];
  const float* bo    = (const float*)d_in[13];

  unsigned short* wsw1s = (unsigned short*)d_ws;            // 8*2*128*64 bf16 = 256 KB
  unsigned short* ats   = wsw1s + 131072;                   // 2*128*64 bf16   = 32 KB
  unsigned short* wcts  = ats + 16384;                      // 128*64 bf16     = 16 KB
  float* bias1          = (float*)(wcts + 8192);            // 8*256 f32       = 8 KB

  setup_k<<<616, 256, 0, stream>>>(A, W_sig, b_sig, W1e, b1e, Wc, wsw1s, ats, wcts, bias1);
  dec_k<<<2048, 512, 0, stream>>>(zs, zcr, reg, W2e, b2e, bcp, Wo, bo,
                                  wsw1s, ats, wcts, bias1, (float*)d_out);
}